// Round 6
// baseline (259.917 us; speedup 1.0000x reference)
//
#include <hip/hip_runtime.h>

typedef __attribute__((ext_vector_type(8))) short bf16x8;
typedef __attribute__((ext_vector_type(4))) float f32x4;

typedef __attribute__((address_space(3))) unsigned int as3_u32;
typedef const __attribute__((address_space(1))) unsigned int as1_u32;

__device__ __forceinline__ unsigned short f2bf(float f) {
    union { float f; unsigned int u; } v; v.f = f;
    unsigned int r = v.u + 0x7fffu + ((v.u >> 16) & 1u);   // RNE
    return (unsigned short)(r >> 16);
}

// pack two f32 -> two bf16 (RNE) in one VALU op
__device__ __forceinline__ unsigned int cvt_pk(float lo, float hi) {
    unsigned int r;
    asm("v_cvt_pk_bf16_f32 %0, %1, %2" : "=v"(r) : "v"(lo), "v"(hi));
    return r;
}
__device__ __forceinline__ unsigned short cvt1(float f) {
    unsigned int r;
    asm("v_cvt_pk_bf16_f32 %0, %1, 0" : "=v"(r) : "v"(f));
    return (unsigned short)r;
}

// Pack W1 (128x256) and W2 (256x128) f32 -> bf16 B-fragment order in ws.
// Frag element (lane l, j) = W[kk*32 + (l>>4)*8 + j][nn*16 + (l&15)].
// W1: frag f = kk*16+nn (kk<4, nn<16) at ws[f*512 ...]; W2 at ws+32768, f = kk*8+nn (kk<8, nn<8).
__global__ void prep_weights(const float* __restrict__ W1, const float* __restrict__ W2,
                             unsigned short* __restrict__ wbuf) {
    int t = blockIdx.x * 256 + threadIdx.x;   // [0, 65536)
    int j = t & 7, l = (t >> 3) & 63, f = (t >> 9) & 63;
    float v;
    if (t < 32768) {
        int kk = f >> 4, nn = f & 15;
        int k = kk * 32 + ((l >> 4) << 3) + j;
        int n = nn * 16 + (l & 15);
        v = W1[k * 256 + n];
    } else {
        int kk = f >> 3, nn = f & 7;
        int k = kk * 32 + ((l >> 4) << 3) + j;
        int n = nn * 16 + (l & 15);
        v = W2[k * 128 + n];
    }
    wbuf[t] = f2bf(v);
}

// Persistent blocks. BM=16 rows/tile, 4 waves. LDS: 2 x (16 x 1040B) raw-f32 x
// double-buffer (global_load_lds dest, 16B row pad -> bank-uniform reads) + 8KB sH.
#define ROW_STRIDE 1040
__global__ __launch_bounds__(256, 3)
void coupling_main(const float* __restrict__ x, const unsigned short* __restrict__ wbuf,
                   const float* __restrict__ b1, const float* __restrict__ b2,
                   float* __restrict__ out, int NT) {
    __shared__ __attribute__((aligned(16))) char sXraw[2][16 * ROW_STRIDE];
    __shared__ unsigned short sH[16 * 256];   // bf16, XOR-swizzled 16B slots

    const int tid = threadIdx.x;
    const int lane = tid & 63;
    const int w = tid >> 6;          // wave 0..3
    const int l15 = lane & 15;
    const int grp = lane >> 4;

    // ---- W1 slice (h-cols 64w..64w+63) register-resident for all tiles ----
    bf16x8 w1f[4][4];
#pragma unroll
    for (int kk = 0; kk < 4; ++kk)
#pragma unroll
      for (int ni = 0; ni < 4; ++ni)
        w1f[kk][ni] = *reinterpret_cast<const bf16x8*>(
            wbuf + ((kk * 16 + 4 * w + ni) * 64 + lane) * 8);
    float b1v[4];
#pragma unroll
    for (int ni = 0; ni < 4; ++ni) b1v[ni] = b1[w * 64 + ni * 16 + l15];
    float b2v[2];
#pragma unroll
    for (int ni = 0; ni < 2; ++ni) b2v[ni] = b2[w * 32 + ni * 16 + l15];

    int tile = blockIdx.x;
    const int stride = gridDim.x;

    // ---- prologue: DMA tile -> buf0 (wave w stages rows 4w..4w+3) ----
    {
        const char* g = (const char*)(x + (size_t)tile * 16 * 256);
#pragma unroll
        for (int j = 0; j < 4; ++j) {
            int row = 4 * w + j;
            __builtin_amdgcn_global_load_lds((as1_u32*)(g + row * 1024 + lane * 16),
                                             (as3_u32*)(&sXraw[0][row * ROW_STRIDE]),
                                             16, 0, 0);
        }
    }
    __syncthreads();
    int cur = 0;

    while (tile < NT) {
        const char* sX = sXraw[cur];

        // ---- phase 2: h = relu(first @ W1 + b1); wave owns h cols 64w..64w+63.
        //      A-frag built from raw f32 LDS with cvt_pk (fused convert). ----
        f32x4 hacc[4];
#pragma unroll
        for (int ni = 0; ni < 4; ++ni) hacc[ni] = (f32x4){0.f, 0.f, 0.f, 0.f};

#pragma unroll
        for (int kk = 0; kk < 4; ++kk) {
            union { unsigned int u[4]; bf16x8 v; } af;
#pragma unroll
            for (int t = 0; t < 4; ++t) {
                const f32x4 ch = *reinterpret_cast<const f32x4*>(
                    sX + l15 * ROW_STRIDE + (16 * kk + 4 * grp + t) * 16);
                af.u[t] = cvt_pk(ch.x, ch.z);   // even elements = first-cols
            }
#pragma unroll
            for (int ni = 0; ni < 4; ++ni)
                hacc[ni] = __builtin_amdgcn_mfma_f32_16x16x32_bf16(af.v, w1f[kk][ni], hacc[ni], 0, 0, 0);
        }

        // ---- h (relu+bias) -> sH via C-layout: row=grp*4+r, col=l&15 ----
#pragma unroll
        for (int ni = 0; ni < 4; ++ni) {
            int col = w * 64 + ni * 16 + l15;
#pragma unroll
            for (int r = 0; r < 4; ++r) {
                int row = grp * 4 + r;
                float hv = fmaxf(hacc[ni][r] + b1v[ni], 0.f);
                int slot = (col >> 3) ^ row;
                sH[row * 256 + slot * 8 + (col & 7)] = cvt1(hv);
            }
        }

        // ---- W2 slice per-tile (anti-LICM opaque pointer keeps VGPR low) ----
        const unsigned short* w2p = wbuf + 32768;
        asm volatile("" : "+v"(w2p));
        bf16x8 w2f[8][2];
#pragma unroll
        for (int kk = 0; kk < 8; ++kk)
#pragma unroll
          for (int ni = 0; ni < 2; ++ni)
            w2f[kk][ni] = *reinterpret_cast<const bf16x8*>(
                w2p + ((kk * 8 + 2 * w + ni) * 64 + lane) * 8);

        __syncthreads();   // h visible to all waves

        // ---- prefetch next tile -> other buffer (after barrier so the
        //      barrier's vmcnt drain doesn't serialize it) ----
        int ntile = tile + stride;
        if (ntile < NT) {
            const char* g = (const char*)(x + (size_t)ntile * 16 * 256);
#pragma unroll
            for (int j = 0; j < 4; ++j) {
                int row = 4 * w + j;
                __builtin_amdgcn_global_load_lds((as1_u32*)(g + row * 1024 + lane * 16),
                                                 (as3_u32*)(&sXraw[cur ^ 1][row * ROW_STRIDE]),
                                                 16, 0, 0);
            }
        }

        // ---- phase 3: m = h @ W2 + b2; wave owns m cols 32w..32w+31 ----
        f32x4 macc[2];
#pragma unroll
        for (int ni = 0; ni < 2; ++ni) macc[ni] = (f32x4){0.f, 0.f, 0.f, 0.f};

#pragma unroll
        for (int kk = 0; kk < 8; ++kk) {
            int slot = (kk * 4 + grp) ^ l15;
            bf16x8 a = *reinterpret_cast<const bf16x8*>(sH + l15 * 256 + slot * 8);
#pragma unroll
            for (int ni = 0; ni < 2; ++ni)
                macc[ni] = __builtin_amdgcn_mfma_f32_16x16x32_bf16(a, w2f[kk][ni], macc[ni], 0, 0, 0);
        }

        // ---- epilogue: out[row][2c] = first[c] (exact f32 from sX),
        //      out[row][2c+1] = second[c] (exact) + m[c] ----
        float* ob = out + (size_t)tile * 16 * 256;
#pragma unroll
        for (int ni = 0; ni < 2; ++ni) {
            int col = w * 32 + ni * 16 + l15;   // [0,128)
#pragma unroll
            for (int r = 0; r < 4; ++r) {
                int row = grp * 4 + r;
                const float2 fs = *reinterpret_cast<const float2*>(
                    sX + row * ROW_STRIDE + col * 8);
                float2 o = make_float2(fs.x, fs.y + macc[ni][r] + b2v[ni]);
                *reinterpret_cast<float2*>(ob + row * 256 + col * 2) = o;
            }
        }

        __syncthreads();   // drains prefetch DMA; protects sH + sX[cur^1] reuse
        tile = ntile;
        cur ^= 1;
    }
}

extern "C" void kernel_launch(void* const* d_in, const int* in_sizes, int n_in,
                              void* d_out, int out_size, void* d_ws, size_t ws_size,
                              hipStream_t stream) {
    const float* x  = (const float*)d_in[0];
    const float* W1 = (const float*)d_in[1];
    const float* b1 = (const float*)d_in[2];
    const float* W2 = (const float*)d_in[3];
    const float* b2 = (const float*)d_in[4];
    float* out = (float*)d_out;
    unsigned short* wbuf = (unsigned short*)d_ws;   // 128 KB

    int NT = in_sizes[0] / (16 * 256);              // 16-row tiles
    prep_weights<<<256, 256, 0, stream>>>(W1, W2, wbuf);
    coupling_main<<<768, 256, 0, stream>>>(x, wbuf, b1, b2, out, NT);
}

// Round 7
// 252.456 us; speedup vs baseline: 1.0296x; 1.0296x over previous
//
#include <hip/hip_runtime.h>

typedef __attribute__((ext_vector_type(8))) short bf16x8;
typedef __attribute__((ext_vector_type(4))) float f32x4;

typedef __attribute__((address_space(3))) unsigned int as3_u32;
typedef const __attribute__((address_space(1))) unsigned int as1_u32;

__device__ __forceinline__ unsigned short f2bf(float f) {
    union { float f; unsigned int u; } v; v.f = f;
    unsigned int r = v.u + 0x7fffu + ((v.u >> 16) & 1u);   // RNE
    return (unsigned short)(r >> 16);
}
// pack two f32 -> two bf16 (RNE) in one VALU op
__device__ __forceinline__ unsigned int cvt_pk(float lo, float hi) {
    unsigned int r;
    asm("v_cvt_pk_bf16_f32 %0, %1, %2" : "=v"(r) : "v"(lo), "v"(hi));
    return r;
}
__device__ __forceinline__ unsigned short cvt1(float f) {
    unsigned int r;
    asm("v_cvt_pk_bf16_f32 %0, %1, 0" : "=v"(r) : "v"(f));
    return (unsigned short)r;
}

// Pack W1 (128x256) and W2 (256x128) f32 -> bf16 B-fragment order in ws.
// Frag element (lane l, j) = W[kk*32 + (l>>4)*8 + j][nn*16 + (l&15)].
// W1: frag f = kk*16+nn (kk<4, nn<16) at ws[f*512 ...]; W2 at ws+32768, f = kk*8+nn (kk<8, nn<8).
__global__ void prep_weights(const float* __restrict__ W1, const float* __restrict__ W2,
                             unsigned short* __restrict__ wbuf) {
    int t = blockIdx.x * 256 + threadIdx.x;   // [0, 65536)
    int j = t & 7, l = (t >> 3) & 63, f = (t >> 9) & 63;
    float v;
    if (t < 32768) {
        int kk = f >> 4, nn = f & 15;
        int k = kk * 32 + ((l >> 4) << 3) + j;
        int n = nn * 16 + (l & 15);
        v = W1[k * 256 + n];
    } else {
        int kk = f >> 3, nn = f & 7;
        int k = kk * 32 + ((l >> 4) << 3) + j;
        int n = nn * 16 + (l & 15);
        v = W2[k * 128 + n];
    }
    wbuf[t] = f2bf(v);
}

// BM=32 rows/tile, 4 waves, persistent blocks. LDS: 2 x 32KB raw-f32 x-tile
// (global_load_lds dest, linear; source pre-swizzled by lane^g(row)) + 16KB sH.
// 80KB -> 2 blocks/CU.
#define BM 32
__global__ __launch_bounds__(256, 2)
void coupling_main(const float* __restrict__ x, const unsigned short* __restrict__ wbuf,
                   const float* __restrict__ b1, const float* __restrict__ b2,
                   float* __restrict__ out, int NT) {
    __shared__ __attribute__((aligned(16))) char sX[2][BM * 1024];   // 64KB
    __shared__ unsigned short sH[BM * 256];                           // 16KB, XOR-swizzled

    const int tid = threadIdx.x;
    const int lane = tid & 63;
    const int w = tid >> 6;          // wave 0..3
    const int l15 = lane & 15;
    const int grp = lane >> 4;

    // ---- weights: loaded ONCE per block, register-resident (R6 lesson) ----
    bf16x8 w1f[4][4];
#pragma unroll
    for (int kk = 0; kk < 4; ++kk)
#pragma unroll
      for (int ni = 0; ni < 4; ++ni)
        w1f[kk][ni] = *reinterpret_cast<const bf16x8*>(
            wbuf + ((kk * 16 + 4 * w + ni) * 64 + lane) * 8);
    bf16x8 w2f[8][2];
#pragma unroll
    for (int kk = 0; kk < 8; ++kk)
#pragma unroll
      for (int ni = 0; ni < 2; ++ni)
        w2f[kk][ni] = *reinterpret_cast<const bf16x8*>(
            wbuf + 32768 + ((kk * 8 + 2 * w + ni) * 64 + lane) * 8);
    float b1v[4];
#pragma unroll
    for (int ni = 0; ni < 4; ++ni) b1v[ni] = b1[w * 64 + ni * 16 + l15];
    float b2v[2];
#pragma unroll
    for (int ni = 0; ni < 2; ++ni) b2v[ni] = b2[w * 32 + ni * 16 + l15];

    const int stride = gridDim.x;
    int tile = blockIdx.x;

    // DMA one 32-row tile into buf; wave w stages rows 8w..8w+7.
    // Source pre-swizzled: LDS slot p holds global 16B-slot p ^ g(row).
#define DMA_TILE(T, BUF)                                                        \
    {                                                                           \
        const char* g = (const char*)(x + (size_t)(T) * (BM * 256));            \
        _Pragma("unroll")                                                       \
        for (int j = 0; j < 8; ++j) {                                           \
            int row = 8 * w + j;                                                \
            int gsw = (row ^ (row >> 3)) & 15;                                  \
            __builtin_amdgcn_global_load_lds(                                   \
                (as1_u32*)(g + row * 1024 + ((lane ^ gsw) << 4)),               \
                (as3_u32*)(&sX[BUF][row * 1024]), 16, 0, 0);                    \
        }                                                                       \
    }

    DMA_TILE(tile, 0)
    __syncthreads();
    int cur = 0;

    while (tile < NT) {
        int nt = tile + stride;
        // prefetch t+1 now; stays in flight across the raw mid-barrier and
        // drains only at the end __syncthreads (T3/T4 counted-wait idea).
        if (nt < NT) DMA_TILE(nt, cur ^ 1)

        const char* sXc = sX[cur];

        // ---- phase 2: h = relu(first @ W1 + b1); wave owns h cols 64w..64w+63 ----
        f32x4 hacc[2][4];
#pragma unroll
        for (int mi = 0; mi < 2; ++mi)
#pragma unroll
          for (int ni = 0; ni < 4; ++ni)
            hacc[mi][ni] = (f32x4){0.f, 0.f, 0.f, 0.f};

#pragma unroll
        for (int mi = 0; mi < 2; ++mi) {
            int row = mi * 16 + l15;
            int gsw = (row ^ (row >> 3)) & 15;
#pragma unroll
            for (int kk = 0; kk < 4; ++kk) {
                union { unsigned int u[4]; bf16x8 v; } af;
#pragma unroll
                for (int t = 0; t < 4; ++t) {
                    int pos = (16 * kk + 4 * grp + t) ^ gsw;
                    const f32x4 ch = *reinterpret_cast<const f32x4*>(
                        sXc + row * 1024 + pos * 16);
                    af.u[t] = cvt_pk(ch.x, ch.z);   // even dwords = first-cols
                }
#pragma unroll
                for (int ni = 0; ni < 4; ++ni)
                    hacc[mi][ni] = __builtin_amdgcn_mfma_f32_16x16x32_bf16(
                        af.v, w1f[kk][ni], hacc[mi][ni], 0, 0, 0);
            }
        }

        // ---- h (relu+bias) -> sH via C-layout: row=mi*16+grp*4+r, col=l&15 ----
#pragma unroll
        for (int mi = 0; mi < 2; ++mi)
#pragma unroll
          for (int ni = 0; ni < 4; ++ni) {
            int col = w * 64 + ni * 16 + l15;
#pragma unroll
            for (int r = 0; r < 4; ++r) {
                int row = mi * 16 + grp * 4 + r;
                float hv = fmaxf(hacc[mi][ni][r] + b1v[ni], 0.f);
                int slot = (col >> 3) ^ (row & 15);
                sH[row * 256 + slot * 8 + (col & 7)] = cvt1(hv);
            }
          }

        // ---- raw mid barrier: lgkm drain only, DMA (vmcnt) stays in flight ----
        asm volatile("s_waitcnt lgkmcnt(0)" ::: "memory");
        __builtin_amdgcn_s_barrier();
        __builtin_amdgcn_sched_barrier(0);

        // ---- phase 3: m = h @ W2 + b2; wave owns m cols 32w..32w+31 ----
        f32x4 macc[2][2];
#pragma unroll
        for (int mi = 0; mi < 2; ++mi)
#pragma unroll
          for (int ni = 0; ni < 2; ++ni)
            macc[mi][ni] = (f32x4){0.f, 0.f, 0.f, 0.f};

#pragma unroll
        for (int mi = 0; mi < 2; ++mi) {
            int row = mi * 16 + l15;
#pragma unroll
            for (int kk = 0; kk < 8; ++kk) {
                int slot = (kk * 4 + grp) ^ l15;
                bf16x8 a = *reinterpret_cast<const bf16x8*>(sH + row * 256 + slot * 8);
#pragma unroll
                for (int ni = 0; ni < 2; ++ni)
                    macc[mi][ni] = __builtin_amdgcn_mfma_f32_16x16x32_bf16(
                        a, w2f[kk][ni], macc[mi][ni], 0, 0, 0);
            }
        }

        // ---- epilogue: first/second exact f32 from sX; out = {f, s+m} ----
        float* ob = out + (size_t)tile * (BM * 256);
#pragma unroll
        for (int mi = 0; mi < 2; ++mi)
#pragma unroll
          for (int ni = 0; ni < 2; ++ni) {
            int col = w * 32 + ni * 16 + l15;   // [0,128)
#pragma unroll
            for (int r = 0; r < 4; ++r) {
                int row = mi * 16 + grp * 4 + r;
                int gsw = (row ^ (row >> 3)) & 15;
                int pos = (col >> 1) ^ gsw;
                const float2 fs = *reinterpret_cast<const float2*>(
                    sXc + row * 1024 + pos * 16 + (col & 1) * 8);
                float2 o = make_float2(fs.x, fs.y + macc[mi][ni][r] + b2v[ni]);
                *reinterpret_cast<float2*>(ob + row * 256 + col * 2) = o;
            }
          }

        __syncthreads();   // drains prefetch DMA; protects sH + sX reuse
        tile = nt;
        cur ^= 1;
    }
}

extern "C" void kernel_launch(void* const* d_in, const int* in_sizes, int n_in,
                              void* d_out, int out_size, void* d_ws, size_t ws_size,
                              hipStream_t stream) {
    const float* x  = (const float*)d_in[0];
    const float* W1 = (const float*)d_in[1];
    const float* b1 = (const float*)d_in[2];
    const float* W2 = (const float*)d_in[3];
    const float* b2 = (const float*)d_in[4];
    float* out = (float*)d_out;
    unsigned short* wbuf = (unsigned short*)d_ws;   // 128 KB

    int NT = in_sizes[0] / (BM * 256);              // 32-row tiles
    prep_weights<<<256, 256, 0, stream>>>(W1, W2, wbuf);
    coupling_main<<<1024, 256, 0, stream>>>(x, wbuf, b1, b2, out, NT);
}

// Round 8
// 116.525 us; speedup vs baseline: 2.2306x; 2.1665x over previous
//
#include <hip/hip_runtime.h>

typedef __attribute__((ext_vector_type(8))) short bf16x8;
typedef __attribute__((ext_vector_type(4))) float f32x4;

__device__ __forceinline__ unsigned short f2bf(float f) {
    union { float f; unsigned int u; } v; v.f = f;
    unsigned int r = v.u + 0x7fffu + ((v.u >> 16) & 1u);   // RNE
    return (unsigned short)(r >> 16);
}
__device__ __forceinline__ float bf2f(unsigned short h) {
    union { unsigned int u; float f; } v; v.u = ((unsigned int)h) << 16;
    return v.f;
}
// pack two f32 -> two bf16 (RNE) in one VALU op (validated R6/R7)
__device__ __forceinline__ unsigned int cvt_pk(float lo, float hi) {
    unsigned int r;
    asm("v_cvt_pk_bf16_f32 %0, %1, %2" : "=v"(r) : "v"(lo), "v"(hi));
    return r;
}

// Pack W1 (128x256) and W2 (256x128) f32 -> bf16 fragment order in ws.
// Frag element (lane l, j) = W[kk*32 + (l>>4)*8 + j][nn*16 + (l&15)].
// W1: frag f = kk*16+nn (kk<4, nn<16) at ws[f*512 ...]; W2 at ws+32768, f = kk*8+nn (kk<8, nn<8).
__global__ void prep_weights(const float* __restrict__ W1, const float* __restrict__ W2,
                             unsigned short* __restrict__ wbuf) {
    int t = blockIdx.x * 256 + threadIdx.x;   // [0, 65536)
    int j = t & 7, l = (t >> 3) & 63, f = (t >> 9) & 63;
    float v;
    if (t < 32768) {
        int kk = f >> 4, nn = f & 15;
        int k = kk * 32 + ((l >> 4) << 3) + j;
        int n = nn * 16 + (l & 15);
        v = W1[k * 256 + n];
    } else {
        int kk = f >> 3, nn = f & 7;
        int k = kk * 32 + ((l >> 4) << 3) + j;
        int n = nn * 16 + (l & 15);
        v = W2[k * 128 + n];
    }
    wbuf[t] = f2bf(v);
}

// BM=64 rows/block, 4 waves, 64KB LDS (R1 skeleton), instruction-dieted.
#define BM 64
__global__ __launch_bounds__(256, 2)
void coupling_main(const float* __restrict__ x, const unsigned short* __restrict__ wbuf,
                   const float* __restrict__ b1, const float* __restrict__ b2,
                   float* __restrict__ out) {
    __shared__ unsigned int sF[BM * 64];    // first  bf16-pairs, 16KB (R1 layout)
    __shared__ unsigned int sS[BM * 64];    // second bf16-pairs, 16KB (R1 layout)
    __shared__ unsigned int sH[BM * 128];   // h bf16 [row][256 cols], 32KB, granule-XOR swizzle

    const int tid = threadIdx.x;
    const int lane = tid & 63;
    const int w = tid >> 6;          // wave 0..3
    const int l15 = lane & 15;
    const int grp = lane >> 4;
    const int row0 = blockIdx.x * BM;

    // ---- W1 fragments: A-operand of swapped phase 2 (same bytes as R1's B use) ----
    bf16x8 w1f[4][4];
#pragma unroll
    for (int kk = 0; kk < 4; ++kk)
#pragma unroll
      for (int nn = 0; nn < 4; ++nn)
        w1f[kk][nn] = *reinterpret_cast<const bf16x8*>(
            wbuf + ((kk * 16 + 4 * w + nn) * 64 + lane) * 8);

    // bias quad: n = w*64 + nn*16 + grp*4 + r  (16B-aligned f32x4 loads)
    f32x4 b1q[4];
#pragma unroll
    for (int nn = 0; nn < 4; ++nn)
        b1q[nn] = *reinterpret_cast<const f32x4*>(b1 + w * 64 + nn * 16 + grp * 4);

    // ---- stage x tile (R1-verified layout, cvt_pk conversions) ----
    const float4* xt = reinterpret_cast<const float4*>(x + (size_t)row0 * 256);
#pragma unroll
    for (int i = 0; i < 16; ++i) {
        int f4 = i * 256 + tid;           // [0,4096)
        float4 v = xt[f4];
        int row = f4 >> 6, c4 = f4 & 63;  // float4 covers x cols 4c4..4c4+3
        int idx = row * 64 + ((c4 >> 2) ^ (row & 15)) * 4 + (c4 & 3);
        sF[idx] = cvt_pk(v.x, v.z);       // first cols 2c4, 2c4+1
        sS[idx] = cvt_pk(v.y, v.w);       // second cols 2c4, 2c4+1
    }
    __syncthreads();

    // ---- phase 2 (swapped): C = W1^T * first^T = h^T.
    //      Lane holds h[xrow = mi*16+l15][n = w*64+nn*16+grp*4+r]. Bias via C-init. ----
    f32x4 hacc[4][4];                     // [nn][mi]
#pragma unroll
    for (int nn = 0; nn < 4; ++nn)
#pragma unroll
      for (int mi = 0; mi < 4; ++mi)
        hacc[nn][mi] = b1q[nn];

#pragma unroll
    for (int mi = 0; mi < 4; ++mi) {
        int row = mi * 16 + l15;
        bf16x8 a4[4];
#pragma unroll
        for (int kk = 0; kk < 4; ++kk) {
            int slot = (kk * 4 + grp) ^ (row & 15);
            a4[kk] = *reinterpret_cast<const bf16x8*>(
                reinterpret_cast<const unsigned short*>(sF) + row * 128 + slot * 8);
        }
#pragma unroll
        for (int kk = 0; kk < 4; ++kk)
#pragma unroll
          for (int nn = 0; nn < 4; ++nn)
            hacc[nn][mi] = __builtin_amdgcn_mfma_f32_16x16x32_bf16(
                w1f[kk][nn], a4[kk], hacc[nn][mi], 0, 0, 0);
    }

    // ---- h (relu) -> sH: lane owns 4 consecutive h-cols -> one ds_write_b64.
    //      u32 granule cg = n>>2 = w*16+nn*4+grp, swizzled by xrow&15. ----
#pragma unroll
    for (int nn = 0; nn < 4; ++nn) {
        int cg = w * 16 + nn * 4 + grp;
#pragma unroll
        for (int mi = 0; mi < 4; ++mi) {
            int xrow = mi * 16 + l15;
            f32x4 hv = hacc[nn][mi];
            uint2 val;
            val.x = cvt_pk(fmaxf(hv.x, 0.f), fmaxf(hv.y, 0.f));
            val.y = cvt_pk(fmaxf(hv.z, 0.f), fmaxf(hv.w, 0.f));
            *reinterpret_cast<uint2*>(sH + xrow * 128 + ((cg ^ (xrow & 15)) << 1)) = val;
        }
    }

    // ---- W2 fragments + b2 (after phase 2 so regalloc can reuse w1f regs) ----
    bf16x8 w2f[8][2];
#pragma unroll
    for (int kk = 0; kk < 8; ++kk)
#pragma unroll
      for (int ni = 0; ni < 2; ++ni)
        w2f[kk][ni] = *reinterpret_cast<const bf16x8*>(
            wbuf + 32768 + ((kk * 8 + 2 * w + ni) * 64 + lane) * 8);
    float b2v[2];
#pragma unroll
    for (int ni = 0; ni < 2; ++ni) b2v[ni] = b2[w * 32 + ni * 16 + l15];

    __syncthreads();

    // ---- phase 3: m = h @ W2 (+b2 via C-init); wave owns m cols 32w..32w+31 ----
    f32x4 macc[4][2];
#pragma unroll
    for (int mi = 0; mi < 4; ++mi)
#pragma unroll
      for (int ni = 0; ni < 2; ++ni)
        macc[mi][ni] = (f32x4){b2v[ni], b2v[ni], b2v[ni], b2v[ni]};

#pragma unroll
    for (int mi = 0; mi < 4; ++mi) {
        int row = mi * 16 + l15;
        int swz = row & 15;
#pragma unroll
        for (int kk = 0; kk < 8; ++kk) {
            int g0 = (kk * 8 + grp * 2) ^ swz;       // granule of k = kk*32+grp*8
            int g1 = (kk * 8 + grp * 2 + 1) ^ swz;   // granule of k+4
            union { unsigned int u[4]; bf16x8 v; } af;
            uint2 p0 = *reinterpret_cast<const uint2*>(sH + row * 128 + g0 * 2);
            uint2 p1 = *reinterpret_cast<const uint2*>(sH + row * 128 + g1 * 2);
            af.u[0] = p0.x; af.u[1] = p0.y; af.u[2] = p1.x; af.u[3] = p1.y;
#pragma unroll
            for (int ni = 0; ni < 2; ++ni)
                macc[mi][ni] = __builtin_amdgcn_mfma_f32_16x16x32_bf16(
                    af.v, w2f[kk][ni], macc[mi][ni], 0, 0, 0);
        }
    }

    // ---- epilogue (R1-verified): out[row][2c]=first[c], out[row][2c+1]=second[c]+m[c] ----
    const unsigned short* sFu = reinterpret_cast<const unsigned short*>(sF);
    const unsigned short* sSu = reinterpret_cast<const unsigned short*>(sS);
#pragma unroll
    for (int mi = 0; mi < 4; ++mi)
#pragma unroll
      for (int ni = 0; ni < 2; ++ni) {
        int col = w * 32 + ni * 16 + l15;   // [0,128)
#pragma unroll
        for (int r = 0; r < 4; ++r) {
            int row = mi * 16 + grp * 4 + r;
            int idx = row * 128 + (((col >> 3) ^ (row & 15)) << 3) + (col & 7);
            float fv = bf2f(sFu[idx]);
            float sv = bf2f(sSu[idx]);
            float2 o = make_float2(fv, sv + macc[mi][ni][r]);
            *reinterpret_cast<float2*>(out + (size_t)(row0 + row) * 256 + col * 2) = o;
        }
      }
}

extern "C" void kernel_launch(void* const* d_in, const int* in_sizes, int n_in,
                              void* d_out, int out_size, void* d_ws, size_t ws_size,
                              hipStream_t stream) {
    const float* x  = (const float*)d_in[0];
    const float* W1 = (const float*)d_in[1];
    const float* b1 = (const float*)d_in[2];
    const float* W2 = (const float*)d_in[3];
    const float* b2 = (const float*)d_in[4];
    float* out = (float*)d_out;
    unsigned short* wbuf = (unsigned short*)d_ws;   // 128 KB

    int Brows = in_sizes[0] / 256;
    prep_weights<<<256, 256, 0, stream>>>(W1, W2, wbuf);
    coupling_main<<<Brows / BM, 256, 0, stream>>>(x, wbuf, b1, b2, out);
}